// Round 1
// baseline (498.591 us; speedup 1.0000x reference)
//
#include <hip/hip_runtime.h>
#include <hip/hip_bf16.h>

#define NN 8192
#define FF 64

typedef _Float16 half8 __attribute__((ext_vector_type(8)));
typedef _Float16 half4v __attribute__((ext_vector_type(4)));
typedef float f32x4 __attribute__((ext_vector_type(4)));

// ---------------------------------------------------------------------------
// Kernel 1: Wh = inputs @ W (fp32 in regs); s = Wh@a_src; d = Wh@a_dst;
// WhT = fp16 transpose of Wh, 80 rows x NN: rows 0..63 = Wh^T, row 64 = 1.0
// (ones column for row-sum via MFMA), rows 65..79 = 0.
// grid 512 blocks x 256 thr; each block does 16 rows; thread = (row, 4 f's).
// ---------------------------------------------------------------------------
__global__ __launch_bounds__(256) void k_prep(const float* __restrict__ inp,
                                              const float* __restrict__ W,
                                              const float* __restrict__ a,
                                              _Float16* __restrict__ WhT,
                                              float* __restrict__ s,
                                              float* __restrict__ d)
{
    __shared__ float Wl[64][64];
    __shared__ float asrc[64], adst[64];
    __shared__ _Float16 tr[64][20];   // [f][16 rows + pad] pad->8B-aligned rows
    const int t = threadIdx.x;
    for (int idx = t; idx < 4096; idx += 256) Wl[idx >> 6][idx & 63] = W[idx];
    if (t < 64) { asrc[t] = a[t]; adst[t] = a[64 + t]; }
    __syncthreads();

    const int rowl = t >> 4;          // 0..15
    const int fg   = t & 15;          // f group: cols fg*4..fg*4+3
    const int row  = blockIdx.x * 16 + rowl;
    const float* ip = inp + (size_t)row * FF;

    float a0 = 0.f, a1 = 0.f, a2 = 0.f, a3 = 0.f;
    #pragma unroll
    for (int k4 = 0; k4 < 16; ++k4) {
        float4 x  = *(const float4*)(ip + k4 * 4);
        float4 w0 = *(const float4*)&Wl[k4 * 4 + 0][fg * 4];
        float4 w1 = *(const float4*)&Wl[k4 * 4 + 1][fg * 4];
        float4 w2 = *(const float4*)&Wl[k4 * 4 + 2][fg * 4];
        float4 w3 = *(const float4*)&Wl[k4 * 4 + 3][fg * 4];
        a0 += x.x * w0.x + x.y * w1.x + x.z * w2.x + x.w * w3.x;
        a1 += x.x * w0.y + x.y * w1.y + x.z * w2.y + x.w * w3.y;
        a2 += x.x * w0.z + x.y * w1.z + x.z * w2.z + x.w * w3.z;
        a3 += x.x * w0.w + x.y * w1.w + x.z * w2.w + x.w * w3.w;
    }

    // s, d partial dots over this thread's 4 features, reduce across fg (16 lanes)
    float sp = a0 * asrc[fg*4] + a1 * asrc[fg*4+1] + a2 * asrc[fg*4+2] + a3 * asrc[fg*4+3];
    float dp = a0 * adst[fg*4] + a1 * adst[fg*4+1] + a2 * adst[fg*4+2] + a3 * adst[fg*4+3];
    #pragma unroll
    for (int msk = 1; msk < 16; msk <<= 1) {
        sp += __shfl_xor(sp, msk);
        dp += __shfl_xor(dp, msk);
    }
    if (fg == 0) { s[row] = sp; d[row] = dp; }

    // fp16 transpose via LDS, then coalesced store of WhT
    tr[fg * 4 + 0][rowl] = (_Float16)a0;
    tr[fg * 4 + 1][rowl] = (_Float16)a1;
    tr[fg * 4 + 2][rowl] = (_Float16)a2;
    tr[fg * 4 + 3][rowl] = (_Float16)a3;
    __syncthreads();
    {
        const int f = t >> 2, seg = t & 3;   // 64 f-rows x 4 segs of 4 halves
        *(half4v*)(WhT + (size_t)f * NN + blockIdx.x * 16 + seg * 4) =
            *(const half4v*)&tr[f][seg * 4];
        // ones row (64) and zero rows (65..79) for this block's 16 columns
        const int fr = 64 + (t >> 4);
        WhT[(size_t)fr * NN + blockIdx.x * 16 + (t & 15)] =
            (_Float16)(((t >> 4) == 0) ? 1.0f : 0.0f);
    }
}

// ---------------------------------------------------------------------------
// Kernel 2: dmax = max(d); c[i] = leakyrelu(s[i] + dmax)  (safe softmax shift)
// ---------------------------------------------------------------------------
__global__ __launch_bounds__(256) void k_shift(const float* __restrict__ s,
                                               const float* __restrict__ d,
                                               float* __restrict__ c)
{
    __shared__ float red[256];
    const int t = threadIdx.x;
    float m = -1e30f;
    for (int i = t; i < NN; i += 256) m = fmaxf(m, d[i]);
    red[t] = m;
    __syncthreads();
    for (int off = 128; off > 0; off >>= 1) {
        if (t < off) red[t] = fmaxf(red[t], red[t + off]);
        __syncthreads();
    }
    const float dmax = red[0];
    for (int i = t; i < NN; i += 256) {
        float x = s[i] + dmax;
        c[i] = fmaxf(x, 0.2f * x);
    }
}

// ---------------------------------------------------------------------------
// p-fragment builder: 4 values of p = adj>0 ? exp(leakyrelu(s+d) - c) : 0
// ---------------------------------------------------------------------------
__device__ __forceinline__ half4v build4(float sv, float cv, int4 aa, float4 dd)
{
    float e0 = sv + dd.x; e0 = fmaxf(e0, 0.2f * e0);
    float e1 = sv + dd.y; e1 = fmaxf(e1, 0.2f * e1);
    float e2 = sv + dd.z; e2 = fmaxf(e2, 0.2f * e2);
    float e3 = sv + dd.w; e3 = fmaxf(e3, 0.2f * e3);
    float p0 = (aa.x > 0) ? __expf(e0 - cv) : 0.0f;
    float p1 = (aa.y > 0) ? __expf(e1 - cv) : 0.0f;
    float p2 = (aa.z > 0) ? __expf(e2 - cv) : 0.0f;
    float p3 = (aa.w > 0) ? __expf(e3 - cv) : 0.0f;
    half4v r;
    r[0] = (_Float16)p0; r[1] = (_Float16)p1;
    r[2] = (_Float16)p2; r[3] = (_Float16)p3;
    return r;
}

// ---------------------------------------------------------------------------
// Kernel 3 (main): block = 16 rows, 4 waves split j into 4x2048.
// P generated on the fly in MFMA A-layout; H-tile + row-sum l via
// mfma_f32_16x16x32_f16 (5 col tiles: 4 features + ones-column).
// Cross-wave combine in LDS, divide by l, ELU, write out.
// ---------------------------------------------------------------------------
__global__ __launch_bounds__(256, 2) void k_main(const int* __restrict__ adj,
                                                 const _Float16* __restrict__ WhT,
                                                 const float* __restrict__ s,
                                                 const float* __restrict__ c,
                                                 const float* __restrict__ dv,
                                                 float* __restrict__ out)
{
    const int tid  = threadIdx.x;
    const int wave = tid >> 6;
    const int lane = tid & 63;
    const int m    = lane & 15;   // MFMA row within tile
    const int g    = lane >> 4;   // k-quad
    const int i0   = blockIdx.x * 16;
    const int row  = i0 + m;

    const float sv = s[row];
    const float cv = c[row];
    const int* arow = adj + (size_t)row * NN;
    const int jstart = wave * 2048;

    f32x4 acc[5];
    #pragma unroll
    for (int n = 0; n < 5; ++n) acc[n] = (f32x4){0.f, 0.f, 0.f, 0.f};

    for (int jt = 0; jt < 2048; jt += 64) {
        const int base = jstart + jt;
        const int jb   = base + g * 8;   // this lane's k-slice start (j index)

        int4   A0a = *(const int4*)(arow + jb);
        int4   A0b = *(const int4*)(arow + jb + 4);
        int4   A1a = *(const int4*)(arow + jb + 32);
        int4   A1b = *(const int4*)(arow + jb + 36);
        float4 D0a = *(const float4*)(dv + jb);
        float4 D0b = *(const float4*)(dv + jb + 4);
        float4 D1a = *(const float4*)(dv + jb + 32);
        float4 D1b = *(const float4*)(dv + jb + 36);

        half4v lo0 = build4(sv, cv, A0a, D0a);
        half4v hi0 = build4(sv, cv, A0b, D0b);
        half4v lo1 = build4(sv, cv, A1a, D1a);
        half4v hi1 = build4(sv, cv, A1b, D1b);
        half8 Af0 = __builtin_shufflevector(lo0, hi0, 0, 1, 2, 3, 4, 5, 6, 7);
        half8 Af1 = __builtin_shufflevector(lo1, hi1, 0, 1, 2, 3, 4, 5, 6, 7);

        half8 B0[5], B1[5];
        #pragma unroll
        for (int n = 0; n < 5; ++n) {
            const _Float16* bp = WhT + (size_t)(n * 16 + m) * NN + jb;
            B0[n] = *(const half8*)(bp);
            B1[n] = *(const half8*)(bp + 32);
        }
        #pragma unroll
        for (int n = 0; n < 5; ++n)
            acc[n] = __builtin_amdgcn_mfma_f32_16x16x32_f16(Af0, B0[n], acc[n], 0, 0, 0);
        #pragma unroll
        for (int n = 0; n < 5; ++n)
            acc[n] = __builtin_amdgcn_mfma_f32_16x16x32_f16(Af1, B1[n], acc[n], 0, 0, 0);
    }

    // ---- cross-wave combine + epilogue ----
    __shared__ float red[4][16][66];
    __shared__ float linv[16];

    #pragma unroll
    for (int n = 0; n < 4; ++n)
        #pragma unroll
        for (int r = 0; r < 4; ++r)
            red[wave][g * 4 + r][n * 16 + m] = acc[n][r];
    if (m == 0) {
        #pragma unroll
        for (int r = 0; r < 4; ++r)
            red[wave][g * 4 + r][64] = acc[4][r];
    }
    __syncthreads();

    if (tid < 16) {
        float l = red[0][tid][64] + red[1][tid][64] + red[2][tid][64] + red[3][tid][64];
        linv[tid] = 1.0f / l;
    }
    __syncthreads();

    {
        const int col = tid & 63;
        const int r0  = tid >> 6;
        #pragma unroll
        for (int rr = 0; rr < 4; ++rr) {
            const int rloc = r0 * 4 + rr;
            float v = red[0][rloc][col] + red[1][rloc][col] +
                      red[2][rloc][col] + red[3][rloc][col];
            v *= linv[rloc];
            out[(size_t)(i0 + rloc) * FF + col] = (v > 0.f) ? v : (__expf(v) - 1.0f);
        }
    }
}

extern "C" void kernel_launch(void* const* d_in, const int* in_sizes, int n_in,
                              void* d_out, int out_size, void* d_ws, size_t ws_size,
                              hipStream_t stream)
{
    const float* inp = (const float*)d_in[0];
    const int*   adj = (const int*)d_in[1];
    const float* W   = (const float*)d_in[2];
    const float* a   = (const float*)d_in[3];
    float* out = (float*)d_out;

    char* ws = (char*)d_ws;
    _Float16* WhT = (_Float16*)ws;                       // 80 * 8192 * 2 B
    float* s  = (float*)(ws + (size_t)80 * NN * 2);      // 8192 f
    float* dv = s + NN;                                  // 8192 f
    float* c  = dv + NN;                                 // 8192 f

    k_prep <<<NN / 16, 256, 0, stream>>>(inp, W, a, WhT, s, dv);
    k_shift<<<1, 256, 0, stream>>>(s, dv, c);
    k_main <<<NN / 16, 256, 0, stream>>>(adj, WhT, s, c, dv, out);
}

// Round 2
// 409.722 us; speedup vs baseline: 1.2169x; 1.2169x over previous
//
#include <hip/hip_runtime.h>
#include <hip/hip_bf16.h>

#define NN 8192
#define FF 64
#define JSPLIT 4
#define JRANGE (NN / JSPLIT)    // 2048 cols per block
#define JT 256                  // cols staged per iteration
#define NIT (JRANGE / JT)       // 8
#define TP 260                  // LDS adj tile row stride (ints), padded
#define PROW 66                 // partial row stride (floats): H[0..63], l at [64]

typedef _Float16 half8 __attribute__((ext_vector_type(8)));
typedef _Float16 half4v __attribute__((ext_vector_type(4)));
typedef float f32x4 __attribute__((ext_vector_type(4)));

__device__ __forceinline__ void async16(const void* g, void* l)
{
    __builtin_amdgcn_global_load_lds(
        (const __attribute__((address_space(1))) unsigned int*)g,
        (__attribute__((address_space(3))) unsigned int*)l, 16, 0, 0);
}

// ---------------------------------------------------------------------------
// Kernel 1: Wh = inputs @ W; s = Wh@a_src; d = Wh@a_dst; WhT fp16 (80 x NN:
// rows 0..63 = Wh^T, row 64 = ones, 65..79 = 0); per-block max(d) partial.
// ---------------------------------------------------------------------------
__global__ __launch_bounds__(256) void k_prep(const float* __restrict__ inp,
                                              const float* __restrict__ W,
                                              const float* __restrict__ a,
                                              _Float16* __restrict__ WhT,
                                              float* __restrict__ s,
                                              float* __restrict__ d,
                                              float* __restrict__ dmax_part)
{
    __shared__ float Wl[64][64];
    __shared__ float asrc[64], adst[64];
    __shared__ _Float16 tr[64][20];
    __shared__ float dmx[16];
    const int t = threadIdx.x;
    for (int idx = t; idx < 4096; idx += 256) Wl[idx >> 6][idx & 63] = W[idx];
    if (t < 64) { asrc[t] = a[t]; adst[t] = a[64 + t]; }
    __syncthreads();

    const int rowl = t >> 4;
    const int fg   = t & 15;
    const int row  = blockIdx.x * 16 + rowl;
    const float* ip = inp + (size_t)row * FF;

    float a0 = 0.f, a1 = 0.f, a2 = 0.f, a3 = 0.f;
    #pragma unroll
    for (int k4 = 0; k4 < 16; ++k4) {
        float4 x  = *(const float4*)(ip + k4 * 4);
        float4 w0 = *(const float4*)&Wl[k4 * 4 + 0][fg * 4];
        float4 w1 = *(const float4*)&Wl[k4 * 4 + 1][fg * 4];
        float4 w2 = *(const float4*)&Wl[k4 * 4 + 2][fg * 4];
        float4 w3 = *(const float4*)&Wl[k4 * 4 + 3][fg * 4];
        a0 += x.x * w0.x + x.y * w1.x + x.z * w2.x + x.w * w3.x;
        a1 += x.x * w0.y + x.y * w1.y + x.z * w2.y + x.w * w3.y;
        a2 += x.x * w0.z + x.y * w1.z + x.z * w2.z + x.w * w3.z;
        a3 += x.x * w0.w + x.y * w1.w + x.z * w2.w + x.w * w3.w;
    }

    float sp = a0 * asrc[fg*4] + a1 * asrc[fg*4+1] + a2 * asrc[fg*4+2] + a3 * asrc[fg*4+3];
    float dp = a0 * adst[fg*4] + a1 * adst[fg*4+1] + a2 * adst[fg*4+2] + a3 * adst[fg*4+3];
    #pragma unroll
    for (int msk = 1; msk < 16; msk <<= 1) {
        sp += __shfl_xor(sp, msk);
        dp += __shfl_xor(dp, msk);
    }
    if (fg == 0) { s[row] = sp; d[row] = dp; dmx[rowl] = dp; }

    tr[fg * 4 + 0][rowl] = (_Float16)a0;
    tr[fg * 4 + 1][rowl] = (_Float16)a1;
    tr[fg * 4 + 2][rowl] = (_Float16)a2;
    tr[fg * 4 + 3][rowl] = (_Float16)a3;
    __syncthreads();
    {
        const int f = t >> 2, seg = t & 3;
        *(half4v*)(WhT + (size_t)f * NN + blockIdx.x * 16 + seg * 4) =
            *(const half4v*)&tr[f][seg * 4];
        const int fr = 64 + (t >> 4);
        WhT[(size_t)fr * NN + blockIdx.x * 16 + (t & 15)] =
            (_Float16)(((t >> 4) == 0) ? 1.0f : 0.0f);
    }
    if (t == 0) {
        float mm = dmx[0];
        #pragma unroll
        for (int i = 1; i < 16; ++i) mm = fmaxf(mm, dmx[i]);
        dmax_part[blockIdx.x] = mm;
    }
}

// ---------------------------------------------------------------------------
// Kernel 2: dmax = max over 512 partials; c[i] = leakyrelu(s[i] + dmax).
// grid 32 x 256, each thread one row.
// ---------------------------------------------------------------------------
__global__ __launch_bounds__(256) void k_shift(const float* __restrict__ s,
                                               const float* __restrict__ dmax_part,
                                               float* __restrict__ c)
{
    __shared__ float red[256];
    const int t = threadIdx.x;
    float m = fmaxf(dmax_part[t], dmax_part[t + 256]);
    red[t] = m;
    __syncthreads();
    for (int off = 128; off > 0; off >>= 1) {
        if (t < off) red[t] = fmaxf(red[t], red[t + off]);
        __syncthreads();
    }
    const float dmax = red[0];
    const int row = blockIdx.x * 256 + t;
    float x = s[row] + dmax;
    c[row] = fmaxf(x, 0.2f * x);
}

__device__ __forceinline__ half4v build4(float sv, float cv, int4 aa, float4 dd)
{
    float e0 = sv + dd.x; e0 = fmaxf(e0, 0.2f * e0);
    float e1 = sv + dd.y; e1 = fmaxf(e1, 0.2f * e1);
    float e2 = sv + dd.z; e2 = fmaxf(e2, 0.2f * e2);
    float e3 = sv + dd.w; e3 = fmaxf(e3, 0.2f * e3);
    float p0 = (aa.x > 0) ? __expf(e0 - cv) : 0.0f;
    float p1 = (aa.y > 0) ? __expf(e1 - cv) : 0.0f;
    float p2 = (aa.z > 0) ? __expf(e2 - cv) : 0.0f;
    float p3 = (aa.w > 0) ? __expf(e3 - cv) : 0.0f;
    half4v r;
    r[0] = (_Float16)p0; r[1] = (_Float16)p1;
    r[2] = (_Float16)p2; r[3] = (_Float16)p3;
    return r;
}

// ---------------------------------------------------------------------------
// Kernel 3 (main): 2048 blocks = 512 row-tiles x 4 j-splits. Block = 16 rows
// x 2048 cols; 8 iters of 256 cols staged to LDS via global_load_lds (one
// fully-coalesced 1KB instruction per adj row). 4 waves split the 256 cols.
// Writes fp32 partial (16 x [64 H | l]) per block.
// ---------------------------------------------------------------------------
__global__ __launch_bounds__(256, 6) void k_main(const int* __restrict__ adj,
                                                 const _Float16* __restrict__ WhT,
                                                 const float* __restrict__ s,
                                                 const float* __restrict__ c,
                                                 const float* __restrict__ dv,
                                                 float* __restrict__ part)
{
    __shared__ union __align__(16) {
        struct { int tile[16][TP]; float dvt[JT]; } st;     // 17664 B
        struct { float red[4][16][66]; } ep;                // 16896 B
    } sm;

    const int tid  = threadIdx.x;
    const int wv   = tid >> 6;
    const int lane = tid & 63;
    const int m    = lane & 15;
    const int g    = lane >> 4;
    const int rt   = blockIdx.x >> 2;
    const int js   = blockIdx.x & 3;
    const int i0   = rt * 16;
    const int j0base = js * JRANGE;
    const int row  = i0 + m;

    const float sv = s[row];
    const float cv = c[row];
    const size_t mrow = (size_t)m * NN;

    f32x4 acc[5];
    #pragma unroll
    for (int n = 0; n < 5; ++n) acc[n] = (f32x4){0.f, 0.f, 0.f, 0.f};

    for (int it = 0; it < NIT; ++it) {
        const int j0 = j0base + it * JT;

        // ---- stage adj tile (16 rows x 256 ints) + dv slice, async to LDS
        {
            const int r0 = wv * 4;
            #pragma unroll
            for (int q = 0; q < 4; ++q) {
                const int r = r0 + q;
                async16(adj + (size_t)(i0 + r) * NN + j0 + lane * 4,
                        &sm.st.tile[r][0]);
            }
            if (wv == 0)
                async16(dv + j0 + lane * 4, &sm.st.dvt[0]);
        }
        __syncthreads();   // drains vmcnt → tile ready

        const int cb = wv * 64 + g * 8;          // this lane's local col slice
        const _Float16* bp = WhT + mrow + (j0 + cb);

        // ---- chunk 0: cols [cb, cb+8)
        {
            int4   A0 = *(const int4*)&sm.st.tile[m][cb];
            int4   A1 = *(const int4*)&sm.st.tile[m][cb + 4];
            float4 D0 = *(const float4*)&sm.st.dvt[cb];
            float4 D1 = *(const float4*)&sm.st.dvt[cb + 4];
            half4v lo = build4(sv, cv, A0, D0);
            half4v hi = build4(sv, cv, A1, D1);
            half8 Af = __builtin_shufflevector(lo, hi, 0, 1, 2, 3, 4, 5, 6, 7);
            #pragma unroll
            for (int n = 0; n < 5; ++n) {
                half8 B = *(const half8*)(bp + (size_t)n * 16 * NN);
                acc[n] = __builtin_amdgcn_mfma_f32_16x16x32_f16(Af, B, acc[n], 0, 0, 0);
            }
        }
        // ---- chunk 1: cols [cb+32, cb+40)
        {
            int4   A0 = *(const int4*)&sm.st.tile[m][cb + 32];
            int4   A1 = *(const int4*)&sm.st.tile[m][cb + 36];
            float4 D0 = *(const float4*)&sm.st.dvt[cb + 32];
            float4 D1 = *(const float4*)&sm.st.dvt[cb + 36];
            half4v lo = build4(sv, cv, A0, D0);
            half4v hi = build4(sv, cv, A1, D1);
            half8 Af = __builtin_shufflevector(lo, hi, 0, 1, 2, 3, 4, 5, 6, 7);
            #pragma unroll
            for (int n = 0; n < 5; ++n) {
                half8 B = *(const half8*)(bp + 32 + (size_t)n * 16 * NN);
                acc[n] = __builtin_amdgcn_mfma_f32_16x16x32_f16(Af, B, acc[n], 0, 0, 0);
            }
        }
        __syncthreads();   // all tile reads done before next stage overwrites
    }

    // ---- cross-wave combine into fp32 partial (reuses LDS via union) ----
    #pragma unroll
    for (int n = 0; n < 4; ++n)
        #pragma unroll
        for (int r = 0; r < 4; ++r)
            sm.ep.red[wv][g * 4 + r][n * 16 + m] = acc[n][r];
    if (m == 0) {
        #pragma unroll
        for (int r = 0; r < 4; ++r)
            sm.ep.red[wv][g * 4 + r][64] = acc[4][r];
    }
    __syncthreads();

    float* pb = part + (size_t)blockIdx.x * (16 * PROW);
    const int col = tid & 63;
    const int r0  = tid >> 6;
    #pragma unroll
    for (int rr = 0; rr < 4; ++rr) {
        const int rl = r0 * 4 + rr;
        pb[rl * PROW + col] = sm.ep.red[0][rl][col] + sm.ep.red[1][rl][col] +
                              sm.ep.red[2][rl][col] + sm.ep.red[3][rl][col];
    }
    if (tid < 16) {
        pb[tid * PROW + 64] = sm.ep.red[0][tid][64] + sm.ep.red[1][tid][64] +
                              sm.ep.red[2][tid][64] + sm.ep.red[3][tid][64];
    }
}

// ---------------------------------------------------------------------------
// Kernel 4: combine 4 j-split partials, divide by l, ELU, write out.
// ---------------------------------------------------------------------------
__global__ __launch_bounds__(256) void k_reduce(const float* __restrict__ part,
                                                float* __restrict__ out)
{
    const int rt  = blockIdx.x;
    const int col = threadIdx.x & 63;
    const int r0  = threadIdx.x >> 6;
    const float* pb = part + (size_t)rt * 4 * (16 * PROW);
    #pragma unroll
    for (int rr = 0; rr < 4; ++rr) {
        const int rl = r0 * 4 + rr;
        float h = 0.f, l = 0.f;
        #pragma unroll
        for (int j = 0; j < 4; ++j) {
            h += pb[(j * 16 + rl) * PROW + col];
            l += pb[(j * 16 + rl) * PROW + 64];
        }
        float v = h / l;
        out[(size_t)(rt * 16 + rl) * FF + col] = (v > 0.f) ? v : (__expf(v) - 1.0f);
    }
}

extern "C" void kernel_launch(void* const* d_in, const int* in_sizes, int n_in,
                              void* d_out, int out_size, void* d_ws, size_t ws_size,
                              hipStream_t stream)
{
    const float* inp = (const float*)d_in[0];
    const int*   adj = (const int*)d_in[1];
    const float* W   = (const float*)d_in[2];
    const float* a   = (const float*)d_in[3];
    float* out = (float*)d_out;

    char* ws = (char*)d_ws;
    _Float16* WhT = (_Float16*)ws;                           // 80*NN*2 = 1,310,720 B
    float* s    = (float*)(ws + (size_t)80 * NN * 2);        // 32 KB
    float* dv   = s + NN;                                    // 32 KB
    float* c    = dv + NN;                                   // 32 KB
    float* dmp  = c + NN;                                    // 512 floats
    float* part = dmp + 512;                                 // 2048*16*66*4 = 8.65 MB

    k_prep  <<<NN / 16, 256, 0, stream>>>(inp, W, a, WhT, s, dv, dmp);
    k_shift <<<32, 256, 0, stream>>>(s, dmp, c);
    k_main  <<<(NN / 16) * JSPLIT, 256, 0, stream>>>(adj, WhT, s, c, dv, part);
    k_reduce<<<NN / 16, 256, 0, stream>>>(part, out);
}

// Round 3
// 408.302 us; speedup vs baseline: 1.2211x; 1.0035x over previous
//
#include <hip/hip_runtime.h>
#include <hip/hip_bf16.h>

#define NN 8192
#define FF 64
#define JSPLIT 4
#define JRANGE (NN / JSPLIT)    // 2048 cols per block
#define JT 256                  // cols staged per iteration
#define NIT (JRANGE / JT)       // 8
#define TP 260                  // LDS adj tile row stride (ints), padded
#define PROW 66                 // partial row stride (floats): H[0..63], l at [64]

typedef _Float16 half8 __attribute__((ext_vector_type(8)));
typedef _Float16 half4v __attribute__((ext_vector_type(4)));
typedef float f32x4 __attribute__((ext_vector_type(4)));

__device__ __forceinline__ void async16(const void* g, void* l)
{
    __builtin_amdgcn_global_load_lds(
        (const __attribute__((address_space(1))) unsigned int*)g,
        (__attribute__((address_space(3))) unsigned int*)l, 16, 0, 0);
}

// ---------------------------------------------------------------------------
// Kernel 1: Wh = inputs @ W; s = Wh@a_src; d = Wh@a_dst; WhT fp16 (80 x NN:
// rows 0..63 = Wh^T, row 64 = ones, 65..79 = 0); per-block max(d) partial.
// ---------------------------------------------------------------------------
__global__ __launch_bounds__(256) void k_prep(const float* __restrict__ inp,
                                              const float* __restrict__ W,
                                              const float* __restrict__ a,
                                              _Float16* __restrict__ WhT,
                                              float* __restrict__ s,
                                              float* __restrict__ d,
                                              float* __restrict__ dmax_part)
{
    __shared__ float Wl[64][64];
    __shared__ float asrc[64], adst[64];
    __shared__ _Float16 tr[64][20];
    __shared__ float dmx[16];
    const int t = threadIdx.x;
    for (int idx = t; idx < 4096; idx += 256) Wl[idx >> 6][idx & 63] = W[idx];
    if (t < 64) { asrc[t] = a[t]; adst[t] = a[64 + t]; }
    __syncthreads();

    const int rowl = t >> 4;
    const int fg   = t & 15;
    const int row  = blockIdx.x * 16 + rowl;
    const float* ip = inp + (size_t)row * FF;

    float a0 = 0.f, a1 = 0.f, a2 = 0.f, a3 = 0.f;
    #pragma unroll
    for (int k4 = 0; k4 < 16; ++k4) {
        float4 x  = *(const float4*)(ip + k4 * 4);
        float4 w0 = *(const float4*)&Wl[k4 * 4 + 0][fg * 4];
        float4 w1 = *(const float4*)&Wl[k4 * 4 + 1][fg * 4];
        float4 w2 = *(const float4*)&Wl[k4 * 4 + 2][fg * 4];
        float4 w3 = *(const float4*)&Wl[k4 * 4 + 3][fg * 4];
        a0 += x.x * w0.x + x.y * w1.x + x.z * w2.x + x.w * w3.x;
        a1 += x.x * w0.y + x.y * w1.y + x.z * w2.y + x.w * w3.y;
        a2 += x.x * w0.z + x.y * w1.z + x.z * w2.z + x.w * w3.z;
        a3 += x.x * w0.w + x.y * w1.w + x.z * w2.w + x.w * w3.w;
    }

    float sp = a0 * asrc[fg*4] + a1 * asrc[fg*4+1] + a2 * asrc[fg*4+2] + a3 * asrc[fg*4+3];
    float dp = a0 * adst[fg*4] + a1 * adst[fg*4+1] + a2 * adst[fg*4+2] + a3 * adst[fg*4+3];
    #pragma unroll
    for (int msk = 1; msk < 16; msk <<= 1) {
        sp += __shfl_xor(sp, msk);
        dp += __shfl_xor(dp, msk);
    }
    if (fg == 0) { s[row] = sp; d[row] = dp; dmx[rowl] = dp; }

    tr[fg * 4 + 0][rowl] = (_Float16)a0;
    tr[fg * 4 + 1][rowl] = (_Float16)a1;
    tr[fg * 4 + 2][rowl] = (_Float16)a2;
    tr[fg * 4 + 3][rowl] = (_Float16)a3;
    __syncthreads();
    {
        const int f = t >> 2, seg = t & 3;
        *(half4v*)(WhT + (size_t)f * NN + blockIdx.x * 16 + seg * 4) =
            *(const half4v*)&tr[f][seg * 4];
        const int fr = 64 + (t >> 4);
        WhT[(size_t)fr * NN + blockIdx.x * 16 + (t & 15)] =
            (_Float16)(((t >> 4) == 0) ? 1.0f : 0.0f);
    }
    if (t == 0) {
        float mm = dmx[0];
        #pragma unroll
        for (int i = 1; i < 16; ++i) mm = fmaxf(mm, dmx[i]);
        dmax_part[blockIdx.x] = mm;
    }
}

// ---------------------------------------------------------------------------
// Kernel 2: dmax = max over 512 partials; c[i] = leakyrelu(s[i] + dmax).
// ---------------------------------------------------------------------------
__global__ __launch_bounds__(256) void k_shift(const float* __restrict__ s,
                                               const float* __restrict__ dmax_part,
                                               float* __restrict__ c)
{
    __shared__ float red[256];
    const int t = threadIdx.x;
    float m = fmaxf(dmax_part[t], dmax_part[t + 256]);
    red[t] = m;
    __syncthreads();
    for (int off = 128; off > 0; off >>= 1) {
        if (t < off) red[t] = fmaxf(red[t], red[t + off]);
        __syncthreads();
    }
    const float dmax = red[0];
    const int row = blockIdx.x * 256 + t;
    float x = s[row] + dmax;
    c[row] = fmaxf(x, 0.2f * x);
}

__device__ __forceinline__ half4v build4(float sv, float cv, int4 aa, float4 dd)
{
    float e0 = sv + dd.x; e0 = fmaxf(e0, 0.2f * e0);
    float e1 = sv + dd.y; e1 = fmaxf(e1, 0.2f * e1);
    float e2 = sv + dd.z; e2 = fmaxf(e2, 0.2f * e2);
    float e3 = sv + dd.w; e3 = fmaxf(e3, 0.2f * e3);
    float p0 = (aa.x > 0) ? __expf(e0 - cv) : 0.0f;
    float p1 = (aa.y > 0) ? __expf(e1 - cv) : 0.0f;
    float p2 = (aa.z > 0) ? __expf(e2 - cv) : 0.0f;
    float p3 = (aa.w > 0) ? __expf(e3 - cv) : 0.0f;
    half4v r;
    r[0] = (_Float16)p0; r[1] = (_Float16)p1;
    r[2] = (_Float16)p2; r[3] = (_Float16)p3;
    return r;
}

// ---------------------------------------------------------------------------
// Kernel 3 (main): 2048 blocks = 512 row-tiles x 4 j-splits. Block = 16 rows
// x 2048 cols; 8 iters of 256 cols, DOUBLE-BUFFERED: prefetch of tile it+1
// issued (global_load_lds) at top of iter it, single barrier per iter drains
// it after compute has covered the latency.
// ---------------------------------------------------------------------------
__global__ __launch_bounds__(256, 4) void k_main(const int* __restrict__ adj,
                                                 const _Float16* __restrict__ WhT,
                                                 const float* __restrict__ s,
                                                 const float* __restrict__ c,
                                                 const float* __restrict__ dv,
                                                 float* __restrict__ part)
{
    __shared__ union __align__(16) {
        struct { int tile[2][16][TP]; float dvt[2][JT]; } st;   // 35328 B
        struct { float red[4][16][66]; } ep;                    // 16896 B
    } sm;

    const int tid  = threadIdx.x;
    const int wv   = tid >> 6;
    const int lane = tid & 63;
    const int m    = lane & 15;
    const int g    = lane >> 4;
    const int rt   = blockIdx.x >> 2;
    const int js   = blockIdx.x & 3;
    const int i0   = rt * 16;
    const int j0base = js * JRANGE;
    const int row  = i0 + m;

    const float sv = s[row];
    const float cv = c[row];
    const size_t mrow = (size_t)m * NN;

    f32x4 acc[5];
    #pragma unroll
    for (int n = 0; n < 5; ++n) acc[n] = (f32x4){0.f, 0.f, 0.f, 0.f};

    // stage tile `it` into buffer `buf` (async, fully coalesced 1KB per instr)
    auto stage = [&](int buf, int it) {
        const int j0 = j0base + it * JT;
        const int r0 = wv * 4;
        #pragma unroll
        for (int q = 0; q < 4; ++q) {
            const int r = r0 + q;
            async16(adj + (size_t)(i0 + r) * NN + j0 + lane * 4,
                    &sm.st.tile[buf][r][0]);
        }
        if (wv == 0)
            async16(dv + j0 + lane * 4, &sm.st.dvt[buf][0]);
    };

    stage(0, 0);
    __syncthreads();           // first tile ready

    for (int it = 0; it < NIT; ++it) {
        const int buf = it & 1;
        if (it + 1 < NIT)
            stage(buf ^ 1, it + 1);          // prefetch next tile (async)

        const int j0 = j0base + it * JT;
        const int cb = wv * 64 + g * 8;
        const _Float16* bp = WhT + mrow + (j0 + cb);

        // ---- chunk 0: cols [cb, cb+8)
        {
            int4   A0 = *(const int4*)&sm.st.tile[buf][m][cb];
            int4   A1 = *(const int4*)&sm.st.tile[buf][m][cb + 4];
            float4 D0 = *(const float4*)&sm.st.dvt[buf][cb];
            float4 D1 = *(const float4*)&sm.st.dvt[buf][cb + 4];
            half4v lo = build4(sv, cv, A0, D0);
            half4v hi = build4(sv, cv, A1, D1);
            half8 Af = __builtin_shufflevector(lo, hi, 0, 1, 2, 3, 4, 5, 6, 7);
            #pragma unroll
            for (int n = 0; n < 5; ++n) {
                half8 B = *(const half8*)(bp + (size_t)n * 16 * NN);
                acc[n] = __builtin_amdgcn_mfma_f32_16x16x32_f16(Af, B, acc[n], 0, 0, 0);
            }
        }
        // ---- chunk 1: cols [cb+32, cb+40)
        {
            int4   A0 = *(const int4*)&sm.st.tile[buf][m][cb + 32];
            int4   A1 = *(const int4*)&sm.st.tile[buf][m][cb + 36];
            float4 D0 = *(const float4*)&sm.st.dvt[buf][cb + 32];
            float4 D1 = *(const float4*)&sm.st.dvt[buf][cb + 36];
            half4v lo = build4(sv, cv, A0, D0);
            half4v hi = build4(sv, cv, A1, D1);
            half8 Af = __builtin_shufflevector(lo, hi, 0, 1, 2, 3, 4, 5, 6, 7);
            #pragma unroll
            for (int n = 0; n < 5; ++n) {
                half8 B = *(const half8*)(bp + 32 + (size_t)n * 16 * NN);
                acc[n] = __builtin_amdgcn_mfma_f32_16x16x32_f16(Af, B, acc[n], 0, 0, 0);
            }
        }
        __syncthreads();   // reads of buf done; prefetch of buf^1 drained
    }

    // ---- cross-wave combine into fp32 partial (reuses LDS via union) ----
    #pragma unroll
    for (int n = 0; n < 4; ++n)
        #pragma unroll
        for (int r = 0; r < 4; ++r)
            sm.ep.red[wv][g * 4 + r][n * 16 + m] = acc[n][r];
    if (m == 0) {
        #pragma unroll
        for (int r = 0; r < 4; ++r)
            sm.ep.red[wv][g * 4 + r][64] = acc[4][r];
    }
    __syncthreads();

    float* pb = part + (size_t)blockIdx.x * (16 * PROW);
    const int col = tid & 63;
    const int r0  = tid >> 6;
    #pragma unroll
    for (int rr = 0; rr < 4; ++rr) {
        const int rl = r0 * 4 + rr;
        pb[rl * PROW + col] = sm.ep.red[0][rl][col] + sm.ep.red[1][rl][col] +
                              sm.ep.red[2][rl][col] + sm.ep.red[3][rl][col];
    }
    if (tid < 16) {
        pb[tid * PROW + 64] = sm.ep.red[0][tid][64] + sm.ep.red[1][tid][64] +
                              sm.ep.red[2][tid][64] + sm.ep.red[3][tid][64];
    }
}

// ---------------------------------------------------------------------------
// Kernel 4: combine 4 j-split partials, divide by l, ELU, write out.
// ---------------------------------------------------------------------------
__global__ __launch_bounds__(256) void k_reduce(const float* __restrict__ part,
                                                float* __restrict__ out)
{
    const int rt  = blockIdx.x;
    const int col = threadIdx.x & 63;
    const int r0  = threadIdx.x >> 6;
    const float* pb = part + (size_t)rt * 4 * (16 * PROW);
    #pragma unroll
    for (int rr = 0; rr < 4; ++rr) {
        const int rl = r0 * 4 + rr;
        float h = 0.f, l = 0.f;
        #pragma unroll
        for (int j = 0; j < 4; ++j) {
            h += pb[(j * 16 + rl) * PROW + col];
            l += pb[(j * 16 + rl) * PROW + 64];
        }
        float v = h / l;
        out[(size_t)(rt * 16 + rl) * FF + col] = (v > 0.f) ? v : (__expf(v) - 1.0f);
    }
}

extern "C" void kernel_launch(void* const* d_in, const int* in_sizes, int n_in,
                              void* d_out, int out_size, void* d_ws, size_t ws_size,
                              hipStream_t stream)
{
    const float* inp = (const float*)d_in[0];
    const int*   adj = (const int*)d_in[1];
    const float* W   = (const float*)d_in[2];
    const float* a   = (const float*)d_in[3];
    float* out = (float*)d_out;

    char* ws = (char*)d_ws;
    _Float16* WhT = (_Float16*)ws;                           // 80*NN*2 = 1,310,720 B
    float* s    = (float*)(ws + (size_t)80 * NN * 2);        // 32 KB
    float* dv   = s + NN;                                    // 32 KB
    float* c    = dv + NN;                                   // 32 KB
    float* dmp  = c + NN;                                    // 512 floats
    float* part = dmp + 512;                                 // 2048*16*66*4 = 8.65 MB

    k_prep  <<<NN / 16, 256, 0, stream>>>(inp, W, a, WhT, s, dv, dmp);
    k_shift <<<32, 256, 0, stream>>>(s, dmp, c);
    k_main  <<<(NN / 16) * JSPLIT, 256, 0, stream>>>(adj, WhT, s, c, dv, part);
    k_reduce<<<NN / 16, 256, 0, stream>>>(part, out);
}